// Round 1
// baseline (699.552 us; speedup 1.0000x reference)
//
#include <hip/hip_runtime.h>
#include <math.h>

// Problem constants (match reference)
#define Bn    16
#define FCH   6
#define NPIX  262144          // 512*512
#define KC    8
#define NITERS 12
#define EPSF  1e-6f
// 2*log2(e)/TEMP : logits in exp2 domain
#define ALPHA2 19.235933878519512f

#if __has_builtin(__builtin_amdgcn_exp2f)
#define EXP2(x) __builtin_amdgcn_exp2f(x)
#else
#define EXP2(x) __expf((x) * 0.6931471805599453f)
#endif

#if __has_builtin(__builtin_amdgcn_rcpf)
#define RCPF(x) __builtin_amdgcn_rcpf(x)
#else
#define RCPF(x) (1.0f / (x))
#endif

// Workspace layout (float offsets)
#define WS_SCALE 0                        // Bn*FCH = 96
#define WS_SHIFT 96                       // 96
#define WS_C     192                      // Bn*KC*FCH = 768 (C0 only)
#define WS_PART  2048                     // 96*32 partial sums
#define WS_PART2 5120                     // 96*32 partial sumsq
#define WS_ACC0  8192                     // 3 buffers x Bn*64 floats (48 accC | 8 accS | pad)
#define ACCBUF_STRIDE 1024                // Bn*64

#define TPB 256
#define PPT 16                            // pixels per thread (was 32)
// assign grid: (NPIX/(TPB*PPT)=64, Bn=16) = 1024 blocks = 4 blocks/CU resident
// at <=128 VGPR (launch_bounds(256,4)) -> 16 waves/CU, 2x the old occupancy.

// force a wave-uniform float into an SGPR (value identical across lanes)
__device__ __forceinline__ float rfl(float x) {
    return __int_as_float(__builtin_amdgcn_readfirstlane(__float_as_int(x)));
}

// ---------------- stage A: partial per-channel sums, 3072 blocks -------------
__global__ __launch_bounds__(256) void stats_partial(const float* __restrict__ feat,
                                                     float* __restrict__ ws) {
    const int bf = blockIdx.x >> 5;
    const int c  = blockIdx.x & 31;
    const float4* p = (const float4*)(feat + (size_t)bf * NPIX) + c * 2048;
    float s = 0.f, ss = 0.f;
    for (int i = threadIdx.x; i < 2048; i += 256) {
        float4 v = p[i];
        s  += v.x + v.y + v.z + v.w;
        ss += v.x * v.x + v.y * v.y + v.z * v.z + v.w * v.w;
    }
#pragma unroll
    for (int off = 32; off > 0; off >>= 1) {
        s  += __shfl_down(s,  off, 64);
        ss += __shfl_down(ss, off, 64);
    }
    __shared__ float sh[8];
    const int w = threadIdx.x >> 6;
    if ((threadIdx.x & 63) == 0) { sh[w] = s; sh[4 + w] = ss; }
    __syncthreads();
    if (threadIdx.x == 0) {
        s  = sh[0] + sh[1] + sh[2] + sh[3];
        ss = sh[4] + sh[5] + sh[6] + sh[7];
        ws[WS_PART  + blockIdx.x] = s;
        ws[WS_PART2 + blockIdx.x] = ss;
    }
}

// ------- stage B: finalize stats, zero acc buffer 0, gather C0 ---------------
__global__ void init_kernel(const float* __restrict__ feat,
                            const int* __restrict__ idx,
                            float* __restrict__ ws) {
    const int t = threadIdx.x;                          // 128 threads
    for (int i = t; i < ACCBUF_STRIDE; i += 128) ws[WS_ACC0 + i] = 0.f;  // buf0
    if (t < Bn * FCH) {
        float s = 0.f, ss = 0.f;
        for (int c = 0; c < 32; ++c) {
            s  += ws[WS_PART  + t * 32 + c];
            ss += ws[WS_PART2 + t * 32 + c];
        }
        float mean = s / (float)NPIX;
        float var  = (ss - s * mean) / (float)(NPIX - 1);   // unbiased (ddof=1)
        float sd   = sqrtf(fmaxf(var, 0.f));
        float scale = 1.f / fmaxf(sd, EPSF);                // ref clips std, not var
        ws[WS_SCALE + t] = scale;
        ws[WS_SHIFT + t] = -mean * scale;
    }
    __syncthreads();
    {   // gather initial (standardized) centroids: thread t = (b,k), Bn*KC = 128
        const int b = t / KC;
        const int n = idx[t];
        for (int f = 0; f < FCH; ++f) {
            const int bf = b * FCH + f;
            float v = fmaf(feat[(size_t)bf * NPIX + n], ws[WS_SCALE + bf], ws[WS_SHIFT + bf]);
            ws[WS_C + t * FCH + f] = v;
        }
    }
}

// ---------------- fused assignment pass (one iteration) ----------------------
// Preamble: build centroids from accRead (or C0 when first), convert to the
// affine logit form  logit2_k = sum_f raw_f*W_kf + bias_k  (exp2 domain; the
// x^2 term is softmax-invariant and dropped; clamp @0 is fp-noise only).
// Accumulation is in RAW pixel space; converted back when folded in next iter.
// W/bias are wave-uniform -> forced into SGPRs (readfirstlane) so the per-thread
// VGPR budget fits 128 (4 blocks/CU).
template <int LAST>
__global__ __launch_bounds__(TPB, 4) void assign_kernel(const float* __restrict__ feat,
                                                        const float* __restrict__ ws,
                                                        float* __restrict__ out,
                                                        float* __restrict__ accAdd,
                                                        const float* __restrict__ accRead,
                                                        float* __restrict__ accZero,
                                                        const int first) {
    const int b = blockIdx.y;
    const int t = threadIdx.x;

    __shared__ float sWb[KC * FCH + KC];       // 48 weights + 8 biases
    __shared__ float sBlk[KC * FCH + KC];

    if (t < KC) {
        float sc[FCH], sh[FCH], C[FCH];
#pragma unroll
        for (int f = 0; f < FCH; ++f) {
            sc[f] = ws[WS_SCALE + b * FCH + f];
            sh[f] = ws[WS_SHIFT + b * FCH + f];
        }
        if (first) {
#pragma unroll
            for (int f = 0; f < FCH; ++f) C[f] = ws[WS_C + (b * KC + t) * FCH + f];
        } else {
            float as  = accRead[b * 64 + 48 + t];
            float inv = 1.f / fmaxf(as, EPSF);
#pragma unroll
            for (int f = 0; f < FCH; ++f)
                C[f] = (sc[f] * accRead[b * 64 + t * FCH + f] + sh[f] * as) * inv;
        }
        float c2 = 0.f, sd = 0.f;
#pragma unroll
        for (int f = 0; f < FCH; ++f) {
            c2 = fmaf(C[f], C[f], c2);
            sd = fmaf(sh[f], C[f], sd);
            sWb[t * FCH + f] = ALPHA2 * sc[f] * C[f];
        }
        sWb[KC * FCH + t] = ALPHA2 * sd - 0.5f * ALPHA2 * c2;
    }
    if (!LAST) {
        if (t < KC * FCH + KC) sBlk[t] = 0.f;
        if (blockIdx.x == 0 && t < 64) accZero[b * 64 + t] = 0.f;   // prep iter+1
    }
    __syncthreads();

    // uniform -> SGPRs
    float W[KC][FCH], bias[KC];
#pragma unroll
    for (int k = 0; k < KC; ++k) {
        bias[k] = rfl(sWb[KC * FCH + k]);
#pragma unroll
        for (int f = 0; f < FCH; ++f) W[k][f] = rfl(sWb[k * FCH + f]);
    }

    const float4* fb4 = (const float4*)(feat + (size_t)b * FCH * NPIX);
    const int base4 = blockIdx.x * (PPT * TPB / 4);     // float4 units

    float accC[KC][FCH], accS[KC];
    if (!LAST) {
#pragma unroll
        for (int k = 0; k < KC; ++k) {
            accS[k] = 0.f;
#pragma unroll
            for (int f = 0; f < FCH; ++f) accC[k][f] = 0.f;
        }
    }

#pragma unroll 1
    for (int j = 0; j < PPT / 4; ++j) {
        const int i4 = base4 + j * TPB + t;
        float rr[FCH][4];
#pragma unroll
        for (int f = 0; f < FCH; ++f) {
            float4 v = fb4[f * (NPIX / 4) + i4];
            rr[f][0] = v.x; rr[f][1] = v.y; rr[f][2] = v.z; rr[f][3] = v.w;
        }
        float sv[KC][4];
#pragma unroll
        for (int px = 0; px < 4; ++px) {
            float l[KC];
#pragma unroll
            for (int k = 0; k < KC; ++k) {
                float v = bias[k];
#pragma unroll
                for (int f = 0; f < FCH; ++f) v = fmaf(rr[f][px], W[k][f], v);
                l[k] = v;
            }
            // pairwise max tree (compiler can fuse into v_max3)
            float m01 = fmaxf(l[0], l[1]), m23 = fmaxf(l[2], l[3]);
            float m45 = fmaxf(l[4], l[5]), m67 = fmaxf(l[6], l[7]);
            float m = fmaxf(fmaxf(m01, m23), fmaxf(m45, m67));
            float e[KC];
#pragma unroll
            for (int k = 0; k < KC; ++k) e[k] = EXP2(l[k] - m);
            float s01 = e[0] + e[1], s23 = e[2] + e[3];
            float s45 = e[4] + e[5], s67 = e[6] + e[7];
            float sum = (s01 + s23) + (s45 + s67);
            const float inv = RCPF(sum);
            if (LAST) {
#pragma unroll
                for (int k = 0; k < KC; ++k) sv[k][px] = e[k] * inv;
            } else {
#pragma unroll
                for (int k = 0; k < KC; ++k) {
                    float s = e[k] * inv;
                    accS[k] += s;
#pragma unroll
                    for (int f = 0; f < FCH; ++f) accC[k][f] = fmaf(s, rr[f][px], accC[k][f]);
                }
            }
        }
        if (LAST) {
            float4* out4 = (float4*)out;
#pragma unroll
            for (int k = 0; k < KC; ++k)
                out4[((size_t)(b * KC + k)) * (NPIX / 4) + i4] =
                    make_float4(sv[k][0], sv[k][1], sv[k][2], sv[k][3]);
        }
    }

    if (!LAST) {
        // wave(64) shuffle reduction of 56 partials -> LDS -> global atomics
#pragma unroll
        for (int k = 0; k < KC; ++k) {
#pragma unroll
            for (int off = 32; off > 0; off >>= 1) accS[k] += __shfl_down(accS[k], off, 64);
#pragma unroll
            for (int f = 0; f < FCH; ++f)
#pragma unroll
                for (int off = 32; off > 0; off >>= 1) accC[k][f] += __shfl_down(accC[k][f], off, 64);
        }
        if ((t & 63) == 0) {            // 4 wave leaders
#pragma unroll
            for (int k = 0; k < KC; ++k) {
                atomicAdd(&sBlk[KC * FCH + k], accS[k]);
#pragma unroll
                for (int f = 0; f < FCH; ++f) atomicAdd(&sBlk[k * FCH + f], accC[k][f]);
            }
        }
        __syncthreads();
        if (t < KC * FCH)
            atomicAdd(&accAdd[b * 64 + t], sBlk[t]);
        else if (t < KC * FCH + KC)
            atomicAdd(&accAdd[b * 64 + 48 + (t - KC * FCH)], sBlk[t]);
    }
}

extern "C" void kernel_launch(void* const* d_in, const int* in_sizes, int n_in,
                              void* d_out, int out_size, void* d_ws, size_t ws_size,
                              hipStream_t stream) {
    const float* feat = (const float*)d_in[0];
    const int*   idx  = (const int*)d_in[1];
    float* out = (float*)d_out;
    float* ws  = (float*)d_ws;

    stats_partial<<<Bn * FCH * 32, 256, 0, stream>>>(feat, ws);   // 3072 blocks
    init_kernel<<<1, 128, 0, stream>>>(feat, idx, ws);            // zeroes buf0

    dim3 grid(NPIX / (PPT * TPB), Bn);          // 64 x 16 = 1024 blocks
    for (int it = 0; it < NITERS; ++it) {
        float*       bufA = ws + WS_ACC0 + (it % 3)       * ACCBUF_STRIDE;  // add
        const float* bufR = ws + WS_ACC0 + ((it + 2) % 3) * ACCBUF_STRIDE;  // read (it-1)
        float*       bufZ = ws + WS_ACC0 + ((it + 1) % 3) * ACCBUF_STRIDE;  // zero (it+1)
        if (it == NITERS - 1)
            assign_kernel<1><<<grid, TPB, 0, stream>>>(feat, ws, out, nullptr, bufR, nullptr, 0);
        else
            assign_kernel<0><<<grid, TPB, 0, stream>>>(feat, ws, out, bufA, bufR, bufZ, it == 0);
    }
}

// Round 3
// 540.663 us; speedup vs baseline: 1.2939x; 1.2939x over previous
//
#include <hip/hip_runtime.h>
#include <math.h>

// Problem constants (match reference)
#define Bn    16
#define FCH   6
#define NPIX  262144          // 512*512
#define KC    8
#define NITERS 12
#define EPSF  1e-6f
// 2*log2(e)/TEMP : logits in exp2 domain
#define ALPHA2 19.235933878519512f

#if __has_builtin(__builtin_amdgcn_exp2f)
#define EXP2(x) __builtin_amdgcn_exp2f(x)
#else
#define EXP2(x) __expf((x) * 0.6931471805599453f)
#endif

#if __has_builtin(__builtin_amdgcn_rcpf)
#define RCPF(x) __builtin_amdgcn_rcpf(x)
#else
#define RCPF(x) (1.0f / (x))
#endif

// Workspace layout (float offsets)
#define WS_SCALE 0                        // Bn*FCH = 96
#define WS_SHIFT 96                       // 96
#define WS_C     192                      // Bn*KC*FCH = 768 (C0 only)
#define WS_PART  2048                     // 96*32 partial sums
#define WS_PART2 5120                     // 96*32 partial sumsq
#define WS_ACC0  8192                     // 3 buffers x Bn*64 floats (48 accC | 8 accS | pad)
#define ACCBUF_STRIDE 1024                // Bn*64

#define TPB 256
#define PPT 32                            // pixels per thread (round-0 known-good)
// assign grid: (NPIX/(TPB*PPT)=32, Bn=16) = 512 blocks, co-resident at 2 blocks/CU

// ---------------- stage A: partial per-channel sums, 3072 blocks -------------
__global__ __launch_bounds__(256) void stats_partial(const float* __restrict__ feat,
                                                     float* __restrict__ ws) {
    const int bf = blockIdx.x >> 5;
    const int c  = blockIdx.x & 31;
    const float4* p = (const float4*)(feat + (size_t)bf * NPIX) + c * 2048;
    float s = 0.f, ss = 0.f;
    for (int i = threadIdx.x; i < 2048; i += 256) {
        float4 v = p[i];
        s  += v.x + v.y + v.z + v.w;
        ss += v.x * v.x + v.y * v.y + v.z * v.z + v.w * v.w;
    }
#pragma unroll
    for (int off = 32; off > 0; off >>= 1) {
        s  += __shfl_down(s,  off, 64);
        ss += __shfl_down(ss, off, 64);
    }
    __shared__ float sh[8];
    const int w = threadIdx.x >> 6;
    if ((threadIdx.x & 63) == 0) { sh[w] = s; sh[4 + w] = ss; }
    __syncthreads();
    if (threadIdx.x == 0) {
        s  = sh[0] + sh[1] + sh[2] + sh[3];
        ss = sh[4] + sh[5] + sh[6] + sh[7];
        ws[WS_PART  + blockIdx.x] = s;
        ws[WS_PART2 + blockIdx.x] = ss;
    }
}

// ------- stage B: finalize stats, zero acc buffer 0, gather C0 ---------------
__global__ void init_kernel(const float* __restrict__ feat,
                            const int* __restrict__ idx,
                            float* __restrict__ ws) {
    const int t = threadIdx.x;                          // 128 threads
    for (int i = t; i < ACCBUF_STRIDE; i += 128) ws[WS_ACC0 + i] = 0.f;  // buf0
    if (t < Bn * FCH) {
        float s = 0.f, ss = 0.f;
        for (int c = 0; c < 32; ++c) {
            s  += ws[WS_PART  + t * 32 + c];
            ss += ws[WS_PART2 + t * 32 + c];
        }
        float mean = s / (float)NPIX;
        float var  = (ss - s * mean) / (float)(NPIX - 1);   // unbiased (ddof=1)
        float sd   = sqrtf(fmaxf(var, 0.f));
        float scale = 1.f / fmaxf(sd, EPSF);                // ref clips std, not var
        ws[WS_SCALE + t] = scale;
        ws[WS_SHIFT + t] = -mean * scale;
    }
    __syncthreads();
    {   // gather initial (standardized) centroids: thread t = (b,k), Bn*KC = 128
        const int b = t / KC;
        const int n = idx[t];
        for (int f = 0; f < FCH; ++f) {
            const int bf = b * FCH + f;
            float v = fmaf(feat[(size_t)bf * NPIX + n], ws[WS_SCALE + bf], ws[WS_SHIFT + bf]);
            ws[WS_C + t * FCH + f] = v;
        }
    }
}

// ---------------- fused assignment pass (one iteration) ----------------------
// Preamble: build centroids from accRead (or C0 when first), convert to the
// affine logit form  logit2_k = sum_f raw_f*W_kf + bias_k  (exp2 domain; the
// x^2 term is softmax-invariant and dropped; clamp @0 is fp-noise only).
// Accumulation is in RAW pixel space; converted back when folded in next iter.
// Main loop is explicitly software-pipelined: iteration j+1's 6 float4 loads
// are issued before iteration j's compute, so the waitcnt lands after ~700
// cycles of independent VALU work (covers HBM/L3 latency at 2 waves/SIMD).
template <int LAST>
__global__ __launch_bounds__(TPB, 2) void assign_kernel(const float* __restrict__ feat,
                                                        const float* __restrict__ ws,
                                                        float* __restrict__ out,
                                                        float* __restrict__ accAdd,
                                                        const float* __restrict__ accRead,
                                                        float* __restrict__ accZero,
                                                        const int first) {
    const int b = blockIdx.y;
    const int t = threadIdx.x;

    __shared__ float sWb[KC * FCH + KC];       // 48 weights + 8 biases
    __shared__ float sBlk[KC * FCH + KC];

    if (t < KC) {
        float sc[FCH], sh[FCH], C[FCH];
#pragma unroll
        for (int f = 0; f < FCH; ++f) {
            sc[f] = ws[WS_SCALE + b * FCH + f];
            sh[f] = ws[WS_SHIFT + b * FCH + f];
        }
        if (first) {
#pragma unroll
            for (int f = 0; f < FCH; ++f) C[f] = ws[WS_C + (b * KC + t) * FCH + f];
        } else {
            float as  = accRead[b * 64 + 48 + t];
            float inv = 1.f / fmaxf(as, EPSF);
#pragma unroll
            for (int f = 0; f < FCH; ++f)
                C[f] = (sc[f] * accRead[b * 64 + t * FCH + f] + sh[f] * as) * inv;
        }
        float c2 = 0.f, sd = 0.f;
#pragma unroll
        for (int f = 0; f < FCH; ++f) {
            c2 = fmaf(C[f], C[f], c2);
            sd = fmaf(sh[f], C[f], sd);
            sWb[t * FCH + f] = ALPHA2 * sc[f] * C[f];
        }
        sWb[KC * FCH + t] = ALPHA2 * sd - 0.5f * ALPHA2 * c2;
    }
    if (!LAST) {
        if (t < KC * FCH + KC) sBlk[t] = 0.f;
        if (blockIdx.x == 0 && t < 64) accZero[b * 64 + t] = 0.f;   // prep iter+1
    }
    __syncthreads();

    float W[KC][FCH], bias[KC];
#pragma unroll
    for (int k = 0; k < KC; ++k) {
        bias[k] = sWb[KC * FCH + k];
#pragma unroll
        for (int f = 0; f < FCH; ++f) W[k][f] = sWb[k * FCH + f];
    }

    const float4* fb4 = (const float4*)(feat + (size_t)b * FCH * NPIX);
    const int base4 = blockIdx.x * (PPT * TPB / 4) + t;   // float4 units

    float accC[KC][FCH], accS[KC];
    if (!LAST) {
#pragma unroll
        for (int k = 0; k < KC; ++k) {
            accS[k] = 0.f;
#pragma unroll
            for (int f = 0; f < FCH; ++f) accC[k][f] = 0.f;
        }
    }

    // prime the pipeline: loads for j=0
    float4 cur[FCH];
#pragma unroll
    for (int f = 0; f < FCH; ++f) cur[f] = fb4[f * (NPIX / 4) + base4];

    for (int j = 0; j < PPT / 4; ++j) {
        // prefetch j+1 (last iteration re-issues its own index j: branchless,
        // stays in-cache, keeps the loop body straight-line with one waitcnt)
        float4 nxt[FCH];
        {
            const int jn = (j + 1 < PPT / 4) ? (j + 1) : j;
            const int i4n = base4 + jn * TPB;
#pragma unroll
            for (int f = 0; f < FCH; ++f) nxt[f] = fb4[f * (NPIX / 4) + i4n];
        }

        float rr[FCH][4];
#pragma unroll
        for (int f = 0; f < FCH; ++f) {
            rr[f][0] = cur[f].x; rr[f][1] = cur[f].y; rr[f][2] = cur[f].z; rr[f][3] = cur[f].w;
        }
        float sv[KC][4];
#pragma unroll
        for (int px = 0; px < 4; ++px) {
            float l[KC];
#pragma unroll
            for (int k = 0; k < KC; ++k) {
                float v = bias[k];
#pragma unroll
                for (int f = 0; f < FCH; ++f) v = fmaf(rr[f][px], W[k][f], v);
                l[k] = v;
            }
            // pairwise max tree (fusable into v_max3)
            float m01 = fmaxf(l[0], l[1]), m23 = fmaxf(l[2], l[3]);
            float m45 = fmaxf(l[4], l[5]), m67 = fmaxf(l[6], l[7]);
            float m = fmaxf(fmaxf(m01, m23), fmaxf(m45, m67));
            float e[KC];
#pragma unroll
            for (int k = 0; k < KC; ++k) e[k] = EXP2(l[k] - m);
            float s01 = e[0] + e[1], s23 = e[2] + e[3];
            float s45 = e[4] + e[5], s67 = e[6] + e[7];
            float sum = (s01 + s23) + (s45 + s67);
            const float inv = RCPF(sum);
            if (LAST) {
#pragma unroll
                for (int k = 0; k < KC; ++k) sv[k][px] = e[k] * inv;
            } else {
#pragma unroll
                for (int k = 0; k < KC; ++k) {
                    float s = e[k] * inv;
                    accS[k] += s;
#pragma unroll
                    for (int f = 0; f < FCH; ++f) accC[k][f] = fmaf(s, rr[f][px], accC[k][f]);
                }
            }
        }
        if (LAST) {
            const int i4 = base4 + j * TPB;
            float4* out4 = (float4*)out;
#pragma unroll
            for (int k = 0; k < KC; ++k)
                out4[((size_t)(b * KC + k)) * (NPIX / 4) + i4] =
                    make_float4(sv[k][0], sv[k][1], sv[k][2], sv[k][3]);
        }

#pragma unroll
        for (int f = 0; f < FCH; ++f) cur[f] = nxt[f];
    }

    if (!LAST) {
        // wave(64) shuffle reduction of 56 partials -> LDS -> global atomics
#pragma unroll
        for (int k = 0; k < KC; ++k) {
#pragma unroll
            for (int off = 32; off > 0; off >>= 1) accS[k] += __shfl_down(accS[k], off, 64);
#pragma unroll
            for (int f = 0; f < FCH; ++f)
#pragma unroll
                for (int off = 32; off > 0; off >>= 1) accC[k][f] += __shfl_down(accC[k][f], off, 64);
        }
        if ((t & 63) == 0) {            // 4 wave leaders
#pragma unroll
            for (int k = 0; k < KC; ++k) {
                atomicAdd(&sBlk[KC * FCH + k], accS[k]);
#pragma unroll
                for (int f = 0; f < FCH; ++f) atomicAdd(&sBlk[k * FCH + f], accC[k][f]);
            }
        }
        __syncthreads();
        if (t < KC * FCH)
            atomicAdd(&accAdd[b * 64 + t], sBlk[t]);
        else if (t < KC * FCH + KC)
            atomicAdd(&accAdd[b * 64 + 48 + (t - KC * FCH)], sBlk[t]);
    }
}

extern "C" void kernel_launch(void* const* d_in, const int* in_sizes, int n_in,
                              void* d_out, int out_size, void* d_ws, size_t ws_size,
                              hipStream_t stream) {
    const float* feat = (const float*)d_in[0];
    const int*   idx  = (const int*)d_in[1];
    float* out = (float*)d_out;
    float* ws  = (float*)d_ws;

    stats_partial<<<Bn * FCH * 32, 256, 0, stream>>>(feat, ws);   // 3072 blocks
    init_kernel<<<1, 128, 0, stream>>>(feat, idx, ws);            // zeroes buf0

    dim3 grid(NPIX / (PPT * TPB), Bn);          // 32 x 16 = 512 blocks
    for (int it = 0; it < NITERS; ++it) {
        float*       bufA = ws + WS_ACC0 + (it % 3)       * ACCBUF_STRIDE;  // add
        const float* bufR = ws + WS_ACC0 + ((it + 2) % 3) * ACCBUF_STRIDE;  // read (it-1)
        float*       bufZ = ws + WS_ACC0 + ((it + 1) % 3) * ACCBUF_STRIDE;  // zero (it+1)
        if (it == NITERS - 1)
            assign_kernel<1><<<grid, TPB, 0, stream>>>(feat, ws, out, nullptr, bufR, nullptr, 0);
        else
            assign_kernel<0><<<grid, TPB, 0, stream>>>(feat, ws, out, bufA, bufR, bufZ, it == 0);
    }
}